// Round 1
// baseline (671.136 us; speedup 1.0000x reference)
//
#include <hip/hip_runtime.h>

// Shapes (fixed): B=2, S=2048, HS=2048, H=16, KV=4, D=128, g=4
// q = hs@Wq^T; k = hs@Wk^T; v = hs@Wv^T; rmsnorm(q,k); rope(q,k);
// scores = qk^T/sqrt(D); softmax; out = (attn@v) @ Wo^T

typedef __attribute__((ext_vector_type(8))) short bf16x8;
typedef __attribute__((ext_vector_type(4))) float f32x4;

__device__ __forceinline__ unsigned short f2bf(float x) {
  union { float f; unsigned u; } v; v.f = x;
  unsigned r = v.u + 0x7fffu + ((v.u >> 16) & 1u);  // RN-even
  return (unsigned short)(r >> 16);
}

__device__ __forceinline__ void gload_lds16(const void* g, void* l) {
  __builtin_amdgcn_global_load_lds(
      (const __attribute__((address_space(1))) void*)g,
      (__attribute__((address_space(3))) void*)l, 16, 0, 0);
}

// ---------------- fp32 -> bf16 convert, 4 elems/thread ----------------
__global__ __launch_bounds__(256) void cvt4(const float4* __restrict__ in,
                                            ushort4* __restrict__ out, int n4) {
  int i = blockIdx.x * 256 + threadIdx.x;
  if (i < n4) {
    float4 v = in[i];
    out[i] = make_ushort4(f2bf(v.x), f2bf(v.y), f2bf(v.z), f2bf(v.w));
  }
}

// ---------------- bf16 GEMM, C[M][N] = sum_k A[m][k]*B[n][k], f32 out ----------------
// 128x128 tile, BK=32, 4 waves (each 64x64 = 4x4 16x16 frags). m97 structure.
__global__ __launch_bounds__(256) void gemm_bt_f32(
    const unsigned short* __restrict__ A, const unsigned short* __restrict__ B,
    float* __restrict__ C, int M, int N, int K) {
  __shared__ unsigned short lsA[128 * 32];
  __shared__ unsigned short lsB[128 * 32];
  const int tid = threadIdx.x;
  const int wave = tid >> 6;
  const int lane = tid & 63;
  const int lrow = lane & 15;
  const int kg = lane >> 4;
  const int nbn = N >> 7;
  const int bm = blockIdx.x / nbn;
  const int bn = blockIdx.x % nbn;
  const int m0 = bm << 7, n0 = bn << 7;
  const int wm = (wave >> 1) << 6, wn = (wave & 1) << 6;
  const f32x4 zero = {0.f, 0.f, 0.f, 0.f};
  f32x4 acc[4][4];
#pragma unroll
  for (int i = 0; i < 4; ++i)
#pragma unroll
    for (int j = 0; j < 4; ++j) acc[i][j] = zero;
  const int srow = tid >> 2;           // (tid*16)/64: row within 64-row half
  const int scol = (tid & 3) << 3;     // element col within 32-wide K slab

  for (int k0 = 0; k0 < K; k0 += 32) {
    __syncthreads();
    // stage 8KB A-tile and B-tile: [128][32] bf16, linear; 2 wave-calls per tile
    gload_lds16(A + (size_t)(m0 + srow) * K + k0 + scol, (char*)lsA + wave * 1024);
    gload_lds16(A + (size_t)(m0 + 64 + srow) * K + k0 + scol, (char*)lsA + 4096 + wave * 1024);
    gload_lds16(B + (size_t)(n0 + srow) * K + k0 + scol, (char*)lsB + wave * 1024);
    gload_lds16(B + (size_t)(n0 + 64 + srow) * K + k0 + scol, (char*)lsB + 4096 + wave * 1024);
    __syncthreads();
    bf16x8 fa[4], fb[4];
#pragma unroll
    for (int i = 0; i < 4; ++i) {
      fa[i] = *(const bf16x8*)(lsA + ((wm + i * 16 + lrow) << 5) + (kg << 3));
      fb[i] = *(const bf16x8*)(lsB + ((wn + i * 16 + lrow) << 5) + (kg << 3));
    }
#pragma unroll
    for (int i = 0; i < 4; ++i)
#pragma unroll
      for (int j = 0; j < 4; ++j)
        acc[i][j] = __builtin_amdgcn_mfma_f32_16x16x32_bf16(fa[i], fb[j], acc[i][j], 0, 0, 0);
  }
  // C/D layout: col = lane&15, row = (lane>>4)*4 + reg  [m89/m91 verified]
#pragma unroll
  for (int i = 0; i < 4; ++i) {
#pragma unroll
    for (int j = 0; j < 4; ++j) {
      int col = n0 + wn + j * 16 + lrow;
      int rbase = m0 + wm + i * 16 + kg * 4;
#pragma unroll
      for (int t = 0; t < 4; ++t)
        C[(size_t)(rbase + t) * N + col] = acc[i][j][t];
    }
  }
}

// ---------------- RMSNorm + RoPE + scale; QKV f32 -> Q/K/V bf16 ----------------
// one wave per (row=b*2048+s, slot); slots: 0..15 q-heads, 16..19 k, 20..23 v
__global__ __launch_bounds__(256) void rms_rope(
    const float* __restrict__ QKV, const float* __restrict__ cosT,
    const float* __restrict__ sinT, const float* __restrict__ wq,
    const float* __restrict__ wk, unsigned short* __restrict__ Q,
    unsigned short* __restrict__ K, unsigned short* __restrict__ V) {
  int task = blockIdx.x * 4 + (threadIdx.x >> 6);
  int lane = threadIdx.x & 63;
  int row = task / 24;
  int slot = task - row * 24;
  int b = row >> 11, s = row & 2047;
  const float* x = QKV + (size_t)row * 3072 + slot * 128;
  float x1 = x[lane], x2 = x[lane + 64];
  if (slot < 20) {
    float ss = x1 * x1 + x2 * x2;
#pragma unroll
    for (int msk = 1; msk < 64; msk <<= 1) ss += __shfl_xor(ss, msk);
    float inv = rsqrtf(ss * (1.0f / 128.0f) + 1e-6f);
    const float* w = (slot < 16) ? wq : wk;
    x1 *= inv * w[lane];
    x2 *= inv * w[lane + 64];
    float c1 = cosT[s * 128 + lane], c2 = cosT[s * 128 + lane + 64];
    float sn1 = sinT[s * 128 + lane], sn2 = sinT[s * 128 + lane + 64];
    float o1 = x1 * c1 - x2 * sn1;   // d < 64: x*c - x[d+64]*s
    float o2 = x2 * c2 + x1 * sn2;   // d >= 64: x*c + x[d-64]*s
    if (slot < 16) { o1 *= 0.08838834764831845f; o2 *= 0.08838834764831845f; }
    x1 = o1; x2 = o2;
  }
  unsigned short* dst;
  if (slot < 16)      dst = Q + (((size_t)b * 16 + slot) * 2048 + s) * 128;
  else if (slot < 20) dst = K + (((size_t)b * 4 + (slot - 16)) * 2048 + s) * 128;
  else                dst = V + (((size_t)b * 4 + (slot - 20)) * 2048 + s) * 128;
  dst[lane] = f2bf(x1);
  dst[lane + 64] = f2bf(x2);
}

// ---------------- flash attention (non-causal), Q pre-scaled by 1/sqrt(D) ------
// block = 4 waves; wave owns 16 q-rows; 32-key tiles; Q(B,H,S,D) K,V(B,KV,S,D)
// O written (B,S,H,D) bf16 for the Wo GEMM.
__global__ __launch_bounds__(256) void attn64(
    const unsigned short* __restrict__ Q, const unsigned short* __restrict__ K,
    const unsigned short* __restrict__ V, unsigned short* __restrict__ O) {
  __shared__ unsigned short Kl[32 * 128];   // [key][d] linear (gload_lds)
  __shared__ unsigned short Vt[128 * 32];   // [d][key] transposed
  __shared__ unsigned short Pl[4][16 * 32]; // per-wave P tile [q][key]
  const int tid = threadIdx.x;
  const int wave = tid >> 6, lane = tid & 63;
  const int lrow = lane & 15, kg = lane >> 4;
  const int bh = blockIdx.x >> 5;
  const int qt = blockIdx.x & 31;
  const int b = bh >> 4, h = bh & 15, kh = h >> 2;  // GQA: h -> h/4
  const unsigned short* Kb = K + ((size_t)(b * 4 + kh) * 2048) * 128;
  const unsigned short* Vb = V + ((size_t)(b * 4 + kh) * 2048) * 128;
  const unsigned short* Qb = Q + ((size_t)(b * 16 + h) * 2048 + qt * 64 + wave * 16) * 128;
  bf16x8 qf[4];
#pragma unroll
  for (int c = 0; c < 4; ++c)
    qf[c] = *(const bf16x8*)(Qb + lrow * 128 + c * 32 + kg * 8);
  const f32x4 zero = {0.f, 0.f, 0.f, 0.f};
  f32x4 acc[8];
#pragma unroll
  for (int c = 0; c < 8; ++c) acc[c] = zero;
  float m[4], l[4];
#pragma unroll
  for (int j = 0; j < 4; ++j) { m[j] = -1e30f; l[j] = 0.f; }

  for (int kt = 0; kt < 2048; kt += 32) {
    __syncthreads();
    // K tile: 32x128 bf16 = 8KB contiguous in global -> linear LDS
    gload_lds16((const char*)(Kb + (size_t)kt * 128) + tid * 16, (char*)Kl + wave * 1024);
    gload_lds16((const char*)(Kb + (size_t)kt * 128) + 4096 + tid * 16,
                (char*)Kl + 4096 + wave * 1024);
    // V tile transposed: Vt[d][key]
#pragma unroll
    for (int r = 0; r < 2; ++r) {
      int t = r * 256 + tid;
      int kk = t >> 4, dc = (t & 15) * 8;
      bf16x8 v = *(const bf16x8*)(Vb + (size_t)(kt + kk) * 128 + dc);
#pragma unroll
      for (int i = 0; i < 8; ++i) Vt[(dc + i) * 32 + kk] = (unsigned short)v[i];
    }
    __syncthreads();
    // S = Q * K^T : two 16x16 tiles (keys 0-15, 16-31), K-dim = 128 (4 mfma each)
    f32x4 s0 = zero, s1 = zero;
#pragma unroll
    for (int c = 0; c < 4; ++c) {
      bf16x8 kb0 = *(const bf16x8*)(Kl + lrow * 128 + c * 32 + kg * 8);
      bf16x8 kb1 = *(const bf16x8*)(Kl + (16 + lrow) * 128 + c * 32 + kg * 8);
      s0 = __builtin_amdgcn_mfma_f32_16x16x32_bf16(qf[c], kb0, s0, 0, 0, 0);
      s1 = __builtin_amdgcn_mfma_f32_16x16x32_bf16(qf[c], kb1, s1, 0, 0, 0);
    }
    // online softmax; D-layout: col(key)=lane&15, row(q)=kg*4+j
#pragma unroll
    for (int j = 0; j < 4; ++j) {
      float mx = fmaxf(s0[j], s1[j]);
#pragma unroll
      for (int msk = 1; msk < 16; msk <<= 1) mx = fmaxf(mx, __shfl_xor(mx, msk));
      float mn = fmaxf(m[j], mx);
      float sc = __expf(m[j] - mn);
      float p0 = __expf(s0[j] - mn);
      float p1 = __expf(s1[j] - mn);
      float sum = p0 + p1;
#pragma unroll
      for (int msk = 1; msk < 16; msk <<= 1) sum += __shfl_xor(sum, msk);
      l[j] = l[j] * sc + sum;
      m[j] = mn;
#pragma unroll
      for (int c = 0; c < 8; ++c) acc[c][j] *= sc;
      Pl[wave][(kg * 4 + j) * 32 + lrow] = f2bf(p0);
      Pl[wave][(kg * 4 + j) * 32 + 16 + lrow] = f2bf(p1);
    }
    // O += P * V : 8 d-chunks, K-dim = 32 keys (1 mfma each)
    bf16x8 pa = *(const bf16x8*)(&Pl[wave][lrow * 32 + kg * 8]);
#pragma unroll
    for (int c = 0; c < 8; ++c) {
      bf16x8 vb = *(const bf16x8*)(Vt + (c * 16 + lrow) * 32 + kg * 8);
      acc[c] = __builtin_amdgcn_mfma_f32_16x16x32_bf16(pa, vb, acc[c], 0, 0, 0);
    }
  }
  // epilogue: O[b][s][h][d] = acc / l
#pragma unroll
  for (int j = 0; j < 4; ++j) {
    float inv = 1.0f / l[j];
    int srow = qt * 64 + wave * 16 + kg * 4 + j;
    unsigned short* dst = O + (((size_t)b * 2048 + srow) * 16 + h) * 128;
#pragma unroll
    for (int c = 0; c < 8; ++c) dst[c * 16 + lrow] = f2bf(acc[c][j] * inv);
  }
}

extern "C" void kernel_launch(void* const* d_in, const int* in_sizes, int n_in,
                              void* d_out, int out_size, void* d_ws, size_t ws_size,
                              hipStream_t stream) {
  const float* hs   = (const float*)d_in[0];
  const float* cosT = (const float*)d_in[1];
  const float* sinT = (const float*)d_in[2];
  const float* Wq   = (const float*)d_in[3];
  const float* Wk   = (const float*)d_in[4];
  const float* Wv   = (const float*)d_in[5];
  const float* Wo   = (const float*)d_in[6];
  const float* nqw  = (const float*)d_in[7];
  const float* nkw  = (const float*)d_in[8];
  float* out = (float*)d_out;

  // workspace layout (bytes): total ~108 MB
  char* ws = (char*)d_ws;
  unsigned short* X    = (unsigned short*)ws;           // 4096x2048 bf16 (16.78MB)
  unsigned short* Wqkv = X + 8388608;                   // 3072x2048 bf16 (12.58MB)
  unsigned short* WoB  = Wqkv + 6291456;                // 2048x2048 bf16 (8.39MB)
  float* QKV           = (float*)(WoB + 4194304);       // 4096x3072 f32  (50.33MB)
  unsigned short* Qb   = (unsigned short*)(QKV + 12582912); // (B,H,S,D) 16.78MB
  unsigned short* Kb   = Qb + 8388608;                  // (B,KV,S,D) 4.19MB
  unsigned short* Vb   = Kb + 2097152;                  // (B,KV,S,D) 4.19MB
  unsigned short* Ob   = (unsigned short*)QKV;          // reuse QKV region (B,S,H,D)

  // 1) converts to bf16
  cvt4<<<8192, 256, 0, stream>>>((const float4*)hs, (ushort4*)X, 2097152);
  cvt4<<<4096, 256, 0, stream>>>((const float4*)Wq, (ushort4*)Wqkv, 1048576);
  cvt4<<<1024, 256, 0, stream>>>((const float4*)Wk, (ushort4*)(Wqkv + 4194304), 262144);
  cvt4<<<1024, 256, 0, stream>>>((const float4*)Wv, (ushort4*)(Wqkv + 5242880), 262144);
  cvt4<<<4096, 256, 0, stream>>>((const float4*)Wo, (ushort4*)WoB, 1048576);

  // 2) QKV = X @ Wqkv^T : M=4096, N=3072, K=2048
  gemm_bt_f32<<<32 * 24, 256, 0, stream>>>(X, Wqkv, QKV, 4096, 3072, 2048);

  // 3) rmsnorm + rope (+ q *= 1/sqrt(D)), reshape to per-head layouts
  rms_rope<<<24576, 256, 0, stream>>>(QKV, cosT, sinT, nqw, nkw, Qb, Kb, Vb);

  // 4) flash attention -> O (B,S,H,D) bf16
  attn64<<<1024, 256, 0, stream>>>(Qb, Kb, Vb, Ob);

  // 5) out = O @ Wo^T : M=4096, N=2048, K=2048 -> f32 d_out
  gemm_bt_f32<<<32 * 16, 256, 0, stream>>>(Ob, WoB, out, 4096, 2048, 2048);
}

// Round 2
// 334.677 us; speedup vs baseline: 2.0053x; 2.0053x over previous
//
#include <hip/hip_runtime.h>

// Shapes (fixed): B=2, S=2048, HS=2048, H=16, KV=4, D=128, g=4

typedef __attribute__((ext_vector_type(8))) short bf16x8;
typedef __attribute__((ext_vector_type(4))) short bf16x4;
typedef __attribute__((ext_vector_type(4))) float f32x4;

__device__ __forceinline__ unsigned short f2bf(float x) {
  union { float f; unsigned u; } v; v.f = x;
  unsigned r = v.u + 0x7fffu + ((v.u >> 16) & 1u);  // RN-even
  return (unsigned short)(r >> 16);
}

__device__ __forceinline__ void gload_lds16(const void* g, void* l) {
  __builtin_amdgcn_global_load_lds(
      (const __attribute__((address_space(1))) void*)g,
      (__attribute__((address_space(3))) void*)l, 16, 0, 0);
}

// ---------------- fp32 -> bf16 convert, 4 elems/thread ----------------
__global__ __launch_bounds__(256) void cvt4(const float4* __restrict__ in,
                                            ushort4* __restrict__ out, int n4) {
  int i = blockIdx.x * 256 + threadIdx.x;
  if (i < n4) {
    float4 v = in[i];
    out[i] = make_ushort4(f2bf(v.x), f2bf(v.y), f2bf(v.z), f2bf(v.w));
  }
}

// ---------------- bf16 GEMM, C[M][N] = sum_k A[m][k]*B[n][k], f32 out ----------------
__global__ __launch_bounds__(256) void gemm_bt_f32(
    const unsigned short* __restrict__ A, const unsigned short* __restrict__ B,
    float* __restrict__ C, int M, int N, int K) {
  __shared__ unsigned short lsA[128 * 32];
  __shared__ unsigned short lsB[128 * 32];
  const int tid = threadIdx.x;
  const int wave = tid >> 6;
  const int lane = tid & 63;
  const int lrow = lane & 15;
  const int kg = lane >> 4;
  const int nbn = N >> 7;
  const int bm = blockIdx.x / nbn;
  const int bn = blockIdx.x % nbn;
  const int m0 = bm << 7, n0 = bn << 7;
  const int wm = (wave >> 1) << 6, wn = (wave & 1) << 6;
  const f32x4 zero = {0.f, 0.f, 0.f, 0.f};
  f32x4 acc[4][4];
#pragma unroll
  for (int i = 0; i < 4; ++i)
#pragma unroll
    for (int j = 0; j < 4; ++j) acc[i][j] = zero;
  const int srow = tid >> 2;
  const int scol = (tid & 3) << 3;

  for (int k0 = 0; k0 < K; k0 += 32) {
    __syncthreads();
    gload_lds16(A + (size_t)(m0 + srow) * K + k0 + scol, (char*)lsA + wave * 1024);
    gload_lds16(A + (size_t)(m0 + 64 + srow) * K + k0 + scol, (char*)lsA + 4096 + wave * 1024);
    gload_lds16(B + (size_t)(n0 + srow) * K + k0 + scol, (char*)lsB + wave * 1024);
    gload_lds16(B + (size_t)(n0 + 64 + srow) * K + k0 + scol, (char*)lsB + 4096 + wave * 1024);
    __syncthreads();
    bf16x8 fa[4], fb[4];
#pragma unroll
    for (int i = 0; i < 4; ++i) {
      fa[i] = *(const bf16x8*)(lsA + ((wm + i * 16 + lrow) << 5) + (kg << 3));
      fb[i] = *(const bf16x8*)(lsB + ((wn + i * 16 + lrow) << 5) + (kg << 3));
    }
#pragma unroll
    for (int i = 0; i < 4; ++i)
#pragma unroll
      for (int j = 0; j < 4; ++j)
        acc[i][j] = __builtin_amdgcn_mfma_f32_16x16x32_bf16(fa[i], fb[j], acc[i][j], 0, 0, 0);
  }
#pragma unroll
  for (int i = 0; i < 4; ++i) {
#pragma unroll
    for (int j = 0; j < 4; ++j) {
      int col = n0 + wn + j * 16 + lrow;
      int rbase = m0 + wm + i * 16 + kg * 4;
#pragma unroll
      for (int t = 0; t < 4; ++t)
        C[(size_t)(rbase + t) * N + col] = acc[i][j][t];
    }
  }
}

// ---------------- RMSNorm + RoPE + scale; writes Q linear, K/V as swizzled 8KB tiles ----
// K tile t of (b,kv): bytes (key*256 + d*2) ^ ((key&7)<<4)           [key = s&31]
// V tile t of (b,kv): TRANSPOSED [d][key]: bytes (d*64 + key*2) ^ (((d>>1)&3)<<4)
__global__ __launch_bounds__(256) void rms_rope(
    const float* __restrict__ QKV, const float* __restrict__ cosT,
    const float* __restrict__ sinT, const float* __restrict__ wq,
    const float* __restrict__ wk, unsigned short* __restrict__ Q,
    unsigned short* __restrict__ Kg, unsigned short* __restrict__ Vg) {
  int task = blockIdx.x * 4 + (threadIdx.x >> 6);
  int lane = threadIdx.x & 63;
  int row = task / 24;
  int slot = task - row * 24;
  int b = row >> 11, s = row & 2047;
  const float* x = QKV + (size_t)row * 3072 + slot * 128;
  float x1 = x[lane], x2 = x[lane + 64];
  if (slot < 20) {
    float ss = x1 * x1 + x2 * x2;
#pragma unroll
    for (int msk = 1; msk < 64; msk <<= 1) ss += __shfl_xor(ss, msk);
    float inv = rsqrtf(ss * (1.0f / 128.0f) + 1e-6f);
    const float* w = (slot < 16) ? wq : wk;
    x1 *= inv * w[lane];
    x2 *= inv * w[lane + 64];
    float c1 = cosT[s * 128 + lane], c2 = cosT[s * 128 + lane + 64];
    float sn1 = sinT[s * 128 + lane], sn2 = sinT[s * 128 + lane + 64];
    float o1 = x1 * c1 - x2 * sn1;
    float o2 = x2 * c2 + x1 * sn2;
    if (slot < 16) { o1 *= 0.08838834764831845f; o2 *= 0.08838834764831845f; }
    x1 = o1; x2 = o2;
  }
  if (slot < 16) {
    unsigned short* dst = Q + (((size_t)b * 16 + slot) * 2048 + s) * 128;
    dst[lane] = f2bf(x1);
    dst[lane + 64] = f2bf(x2);
  } else {
    int kv = (slot - 16) & 3;
    size_t tb = ((size_t)((b * 4 + kv) * 64) + (s >> 5)) * 8192;  // tile base bytes
    int key = s & 31;
    if (slot < 20) {
      char* base = (char*)Kg + tb;
      int xr = (key & 7) << 4;
      *(unsigned short*)(base + ((key * 256 + lane * 2) ^ xr)) = f2bf(x1);
      *(unsigned short*)(base + ((key * 256 + (lane + 64) * 2) ^ xr)) = f2bf(x2);
    } else {
      char* base = (char*)Vg + tb;
      int d1 = lane, d2 = lane + 64;
      *(unsigned short*)(base + ((d1 * 64 + key * 2) ^ (((d1 >> 1) & 3) << 4))) = f2bf(x1);
      *(unsigned short*)(base + ((d2 * 64 + key * 2) ^ (((d2 >> 1) & 3) << 4))) = f2bf(x2);
    }
  }
}

// ---------------- flash attention, swapped-QK^T, in-register P, dbuf K/V ----------
__global__ __launch_bounds__(256) void attn64(
    const unsigned short* __restrict__ Q, const unsigned short* __restrict__ Kg,
    const unsigned short* __restrict__ Vg, unsigned short* __restrict__ O) {
  __shared__ unsigned short Kl[2][4096];
  __shared__ unsigned short Vl[2][4096];
  const int tid = threadIdx.x;
  const int wave = tid >> 6, lane = tid & 63;
  const int lrow = lane & 15, kg = lane >> 4;
  int bid = blockIdx.x;
  bid = (bid & 7) * 128 + (bid >> 3);  // XCD swizzle: 1024 % 8 == 0, bijective
  const int bh = bid >> 5, qt = bid & 31;
  const int b = bh >> 4, h = bh & 15, kh = h >> 2;
  const char* Kt = (const char*)Kg + (size_t)((b * 4 + kh) * 64) * 8192;
  const char* Vt = (const char*)Vg + (size_t)((b * 4 + kh) * 64) * 8192;
  const unsigned short* Qb = Q + ((size_t)(b * 16 + h) * 2048 + qt * 64 + wave * 16) * 128;
  bf16x8 qf[4];
#pragma unroll
  for (int c = 0; c < 4; ++c)
    qf[c] = *(const bf16x8*)(Qb + lrow * 128 + c * 32 + kg * 8);
  const f32x4 zero = {0.f, 0.f, 0.f, 0.f};
  f32x4 acc[8];
#pragma unroll
  for (int c = 0; c < 8; ++c) acc[c] = zero;
  float m = -1e30f, l = 0.f;

  const int o1 = wave * 1024 + lane * 16;
  const int o2 = 4096 + wave * 1024 + lane * 16;
  const int d1 = wave * 1024;          // LDS dest bases (wave-uniform)
  const int d2 = 4096 + wave * 1024;

  // prologue: stage tile 0 into buf 0
  gload_lds16(Kt + o1, (char*)Kl[0] + d1);
  gload_lds16(Kt + o2, (char*)Kl[0] + d2);
  gload_lds16(Vt + o1, (char*)Vl[0] + d1);
  gload_lds16(Vt + o2, (char*)Vl[0] + d2);
  __syncthreads();

  for (int t = 0; t < 64; ++t) {
    const int cur = t & 1;
    if (t < 63) {  // stage next tile into other buffer (drained at loop-end sync)
      const char* kt = Kt + (size_t)(t + 1) * 8192;
      const char* vt = Vt + (size_t)(t + 1) * 8192;
      gload_lds16(kt + o1, (char*)Kl[cur ^ 1] + d1);
      gload_lds16(kt + o2, (char*)Kl[cur ^ 1] + d2);
      gload_lds16(vt + o1, (char*)Vl[cur ^ 1] + d1);
      gload_lds16(vt + o2, (char*)Vl[cur ^ 1] + d2);
    }
    const unsigned short* Kb = Kl[cur];
    const unsigned short* Vb = Vl[cur];
    // S^T = K * Q^T : rows = keys, cols = q.  s0: keys 0-15, s1: keys 16-31.
    f32x4 s0 = zero, s1 = zero;
    __builtin_amdgcn_s_setprio(1);
#pragma unroll
    for (int c = 0; c < 4; ++c) {
      const int xr = (lrow & 7) << 4;
      bf16x8 k0 = *(const bf16x8*)((const char*)Kb + ((lrow * 256 + c * 64 + kg * 16) ^ xr));
      bf16x8 k1 = *(const bf16x8*)((const char*)Kb + (((16 + lrow) * 256 + c * 64 + kg * 16) ^ xr));
      s0 = __builtin_amdgcn_mfma_f32_16x16x32_bf16(k0, qf[c], s0, 0, 0, 0);
      s1 = __builtin_amdgcn_mfma_f32_16x16x32_bf16(k1, qf[c], s1, 0, 0, 0);
    }
    __builtin_amdgcn_s_setprio(0);
    // lane holds S[key = t*32 + kg*4+j (+16)][q = lrow]: per-q stats live on lane (q=lrow)
    float mx = fmaxf(fmaxf(fmaxf(s0[0], s0[1]), fmaxf(s0[2], s0[3])),
                     fmaxf(fmaxf(s1[0], s1[1]), fmaxf(s1[2], s1[3])));
    mx = fmaxf(mx, __shfl_xor(mx, 16));
    mx = fmaxf(mx, __shfl_xor(mx, 32));
    float sc = 1.f;
    if (__any(mx > m + 8.f)) {  // defer-max (T13): rescale only on real growth
      float mn = fmaxf(m, mx);
      sc = __expf(m - mn);
      m = mn;
#pragma unroll
      for (int j = 0; j < 4; ++j) {
        float scq = __shfl(sc, (lane & 48) | (kg * 4 + j));
#pragma unroll
        for (int c = 0; c < 8; ++c) acc[c][j] *= scq;
      }
    }
    float p0[4], p1[4], sum = 0.f;
#pragma unroll
    for (int j = 0; j < 4; ++j) {
      p0[j] = __expf(s0[j] - m);
      p1[j] = __expf(s1[j] - m);
      sum += p0[j] + p1[j];
    }
    sum += __shfl_xor(sum, 16);
    sum += __shfl_xor(sum, 32);
    l = l * sc + sum;
    // P fragment is already lane-local: element i<4 = key kg*4+i, i>=4 = key 16+kg*4+(i-4)
    bf16x8 pa;
#pragma unroll
    for (int j = 0; j < 4; ++j) {
      pa[j] = (short)f2bf(p0[j]);
      pa[4 + j] = (short)f2bf(p1[j]);
    }
    __builtin_amdgcn_s_setprio(1);
#pragma unroll
    for (int c = 0; c < 8; ++c) {
      int drow = c * 16 + lrow;
      int xv = ((drow >> 1) & 3) << 4;
      bf16x4 va = *(const bf16x4*)((const char*)Vb + ((drow * 64 + kg * 8) ^ xv));
      bf16x4 vb2 = *(const bf16x4*)((const char*)Vb + ((drow * 64 + 32 + kg * 8) ^ xv));
      bf16x8 vf;
      vf[0] = va[0]; vf[1] = va[1]; vf[2] = va[2]; vf[3] = va[3];
      vf[4] = vb2[0]; vf[5] = vb2[1]; vf[6] = vb2[2]; vf[7] = vb2[3];
      acc[c] = __builtin_amdgcn_mfma_f32_16x16x32_bf16(pa, vf, acc[c], 0, 0, 0);
    }
    __builtin_amdgcn_s_setprio(0);
    __syncthreads();  // drains vmcnt(0): next tile ready; buffers safe to swap
  }
  // epilogue: acc[c][j] = O[q = kg*4+j][d = c*16+lrow]
  float inv = 1.0f / l;
#pragma unroll
  for (int j = 0; j < 4; ++j) {
    float invq = __shfl(inv, (lane & 48) | (kg * 4 + j));
    int srow = qt * 64 + wave * 16 + kg * 4 + j;
    unsigned short* dst = O + (((size_t)b * 2048 + srow) * 16 + h) * 128;
#pragma unroll
    for (int c = 0; c < 8; ++c) dst[c * 16 + lrow] = f2bf(acc[c][j] * invq);
  }
}

extern "C" void kernel_launch(void* const* d_in, const int* in_sizes, int n_in,
                              void* d_out, int out_size, void* d_ws, size_t ws_size,
                              hipStream_t stream) {
  const float* hs   = (const float*)d_in[0];
  const float* cosT = (const float*)d_in[1];
  const float* sinT = (const float*)d_in[2];
  const float* Wq   = (const float*)d_in[3];
  const float* Wk   = (const float*)d_in[4];
  const float* Wv   = (const float*)d_in[5];
  const float* Wo   = (const float*)d_in[6];
  const float* nqw  = (const float*)d_in[7];
  const float* nkw  = (const float*)d_in[8];
  float* out = (float*)d_out;

  char* ws = (char*)d_ws;
  unsigned short* X    = (unsigned short*)ws;               // 4096x2048 bf16
  unsigned short* Wqkv = X + 8388608;                       // 3072x2048 bf16
  unsigned short* WoB  = Wqkv + 6291456;                    // 2048x2048 bf16
  float* QKV           = (float*)(WoB + 4194304);           // 4096x3072 f32
  unsigned short* Qb   = (unsigned short*)(QKV + 12582912); // (B,H,S,D)
  unsigned short* Kg   = Qb + 8388608;                      // swizzled tiles 4.19MB
  unsigned short* Vg   = Kg + 2097152;                      // swizzled tiles 4.19MB
  unsigned short* Ob   = (unsigned short*)QKV;              // reuse QKV region

  cvt4<<<8192, 256, 0, stream>>>((const float4*)hs, (ushort4*)X, 2097152);
  cvt4<<<4096, 256, 0, stream>>>((const float4*)Wq, (ushort4*)Wqkv, 1048576);
  cvt4<<<1024, 256, 0, stream>>>((const float4*)Wk, (ushort4*)(Wqkv + 4194304), 262144);
  cvt4<<<1024, 256, 0, stream>>>((const float4*)Wv, (ushort4*)(Wqkv + 5242880), 262144);
  cvt4<<<4096, 256, 0, stream>>>((const float4*)Wo, (ushort4*)WoB, 1048576);

  gemm_bt_f32<<<32 * 24, 256, 0, stream>>>(X, Wqkv, QKV, 4096, 3072, 2048);

  rms_rope<<<24576, 256, 0, stream>>>(QKV, cosT, sinT, nqw, nkw, Qb, Kg, Vg);

  attn64<<<1024, 256, 0, stream>>>(Qb, Kg, Vg, Ob);

  gemm_bt_f32<<<32 * 16, 256, 0, stream>>>(Ob, WoB, out, 4096, 2048, 2048);
}

// Round 3
// 278.330 us; speedup vs baseline: 2.4113x; 1.2024x over previous
//
#include <hip/hip_runtime.h>

// Shapes (fixed): B=2, S=2048, HS=2048, H=16, KV=4, D=128, g=4

typedef __attribute__((ext_vector_type(8))) short bf16x8;
typedef __attribute__((ext_vector_type(4))) float f32x4;

__device__ __forceinline__ unsigned short f2bf(float x) {
  union { float f; unsigned u; } v; v.f = x;
  unsigned r = v.u + 0x7fffu + ((v.u >> 16) & 1u);  // RN-even
  return (unsigned short)(r >> 16);
}

__device__ __forceinline__ unsigned cvt_pk_bf16(float lo, float hi) {
  unsigned r;
  asm("v_cvt_pk_bf16_f32 %0, %1, %2" : "=v"(r) : "v"(lo), "v"(hi));
  return r;
}

__device__ __forceinline__ void gload_lds16(const void* g, void* l) {
  __builtin_amdgcn_global_load_lds(
      (const __attribute__((address_space(1))) void*)g,
      (__attribute__((address_space(3))) void*)l, 16, 0, 0);
}

// ---------------- fp32 -> bf16 convert, 4 elems/thread ----------------
__global__ __launch_bounds__(256) void cvt4(const float4* __restrict__ in,
                                            ushort4* __restrict__ out, int n4) {
  int i = blockIdx.x * 256 + threadIdx.x;
  if (i < n4) {
    float4 v = in[i];
    out[i] = make_ushort4(f2bf(v.x), f2bf(v.y), f2bf(v.z), f2bf(v.w));
  }
}

// ---------------- bf16 GEMM, C[M][N] = sum_k A[m][k]*B[n][k], f32 out ----------------
__global__ __launch_bounds__(256) void gemm_bt_f32(
    const unsigned short* __restrict__ A, const unsigned short* __restrict__ B,
    float* __restrict__ C, int M, int N, int K) {
  __shared__ unsigned short lsA[128 * 32];
  __shared__ unsigned short lsB[128 * 32];
  const int tid = threadIdx.x;
  const int wave = tid >> 6;
  const int lane = tid & 63;
  const int lrow = lane & 15;
  const int kg = lane >> 4;
  const int nbn = N >> 7;
  const int bm = blockIdx.x / nbn;
  const int bn = blockIdx.x % nbn;
  const int m0 = bm << 7, n0 = bn << 7;
  const int wm = (wave >> 1) << 6, wn = (wave & 1) << 6;
  const f32x4 zero = {0.f, 0.f, 0.f, 0.f};
  f32x4 acc[4][4];
#pragma unroll
  for (int i = 0; i < 4; ++i)
#pragma unroll
    for (int j = 0; j < 4; ++j) acc[i][j] = zero;
  const int srow = tid >> 2;
  const int scol = (tid & 3) << 3;

  for (int k0 = 0; k0 < K; k0 += 32) {
    __syncthreads();
    gload_lds16(A + (size_t)(m0 + srow) * K + k0 + scol, (char*)lsA + wave * 1024);
    gload_lds16(A + (size_t)(m0 + 64 + srow) * K + k0 + scol, (char*)lsA + 4096 + wave * 1024);
    gload_lds16(B + (size_t)(n0 + srow) * K + k0 + scol, (char*)lsB + wave * 1024);
    gload_lds16(B + (size_t)(n0 + 64 + srow) * K + k0 + scol, (char*)lsB + 4096 + wave * 1024);
    __syncthreads();
    bf16x8 fa[4], fb[4];
#pragma unroll
    for (int i = 0; i < 4; ++i) {
      fa[i] = *(const bf16x8*)(lsA + ((wm + i * 16 + lrow) << 5) + (kg << 3));
      fb[i] = *(const bf16x8*)(lsB + ((wn + i * 16 + lrow) << 5) + (kg << 3));
    }
#pragma unroll
    for (int i = 0; i < 4; ++i)
#pragma unroll
      for (int j = 0; j < 4; ++j)
        acc[i][j] = __builtin_amdgcn_mfma_f32_16x16x32_bf16(fa[i], fb[j], acc[i][j], 0, 0, 0);
  }
#pragma unroll
  for (int i = 0; i < 4; ++i) {
#pragma unroll
    for (int j = 0; j < 4; ++j) {
      int col = n0 + wn + j * 16 + lrow;
      int rbase = m0 + wm + i * 16 + kg * 4;
#pragma unroll
      for (int t = 0; t < 4; ++t)
        C[(size_t)(rbase + t) * N + col] = acc[i][j][t];
    }
  }
}

// ---------------- RMSNorm + RoPE + scale; Q linear, K/V as pre-baked 8KB tiles ----
// K tile t of (b,kv): bytes key*256 + (d*2 ^ ((key&7)<<4))                [key=s&31]
// V tile t of (b,kv): TRANSPOSED [d][pos]: bytes d*64 + pos*2,
//   pos = (key&12)*2 + (key&3) + ((key>>4)<<2)  (interleaves keys k,k+16 for b128 PV reads)
// Q pre-scaled by D^-1/2 * log2(e)  (attention softmax runs in exp2 domain)
__global__ __launch_bounds__(256) void rms_rope(
    const float* __restrict__ QKV, const float* __restrict__ cosT,
    const float* __restrict__ sinT, const float* __restrict__ wq,
    const float* __restrict__ wk, unsigned short* __restrict__ Q,
    unsigned short* __restrict__ Kg, unsigned short* __restrict__ Vg) {
  int task = blockIdx.x * 4 + (threadIdx.x >> 6);
  int lane = threadIdx.x & 63;
  int row = task / 24;
  int slot = task - row * 24;
  int b = row >> 11, s = row & 2047;
  const float* x = QKV + (size_t)row * 3072 + slot * 128;
  float x1 = x[lane], x2 = x[lane + 64];
  if (slot < 20) {
    float ss = x1 * x1 + x2 * x2;
#pragma unroll
    for (int msk = 1; msk < 64; msk <<= 1) ss += __shfl_xor(ss, msk);
    float inv = rsqrtf(ss * (1.0f / 128.0f) + 1e-6f);
    const float* w = (slot < 16) ? wq : wk;
    x1 *= inv * w[lane];
    x2 *= inv * w[lane + 64];
    float c1 = cosT[s * 128 + lane], c2 = cosT[s * 128 + lane + 64];
    float sn1 = sinT[s * 128 + lane], sn2 = sinT[s * 128 + lane + 64];
    float o1 = x1 * c1 - x2 * sn1;
    float o2 = x2 * c2 + x1 * sn2;
    if (slot < 16) {
      const float qs = 0.08838834764831845f * 1.4426950408889634f;  // D^-1/2 * log2(e)
      o1 *= qs; o2 *= qs;
    }
    x1 = o1; x2 = o2;
  }
  if (slot < 16) {
    unsigned short* dst = Q + (((size_t)b * 16 + slot) * 2048 + s) * 128;
    dst[lane] = f2bf(x1);
    dst[lane + 64] = f2bf(x2);
  } else {
    int kv = (slot - 16) & 3;
    size_t tb = ((size_t)((b * 4 + kv) * 64) + (s >> 5)) * 8192;  // tile base bytes
    int key = s & 31;
    if (slot < 20) {
      char* base = (char*)Kg + tb;
      int xr = (key & 7) << 4;
      *(unsigned short*)(base + key * 256 + ((lane * 2) ^ xr)) = f2bf(x1);
      *(unsigned short*)(base + key * 256 + (((lane + 64) * 2) ^ xr)) = f2bf(x2);
    } else {
      char* base = (char*)Vg + tb;
      int pos = ((key & 12) << 1) + (key & 3) + ((key >> 4) << 2);
      *(unsigned short*)(base + lane * 64 + pos * 2) = f2bf(x1);
      *(unsigned short*)(base + (lane + 64) * 64 + pos * 2) = f2bf(x2);
    }
  }
}

// ---------------- flash attention: swapped-QK^T, 2 q-frags/wave, in-register P ----
__global__ __launch_bounds__(256, 2) void attn64(
    const unsigned short* __restrict__ Q, const unsigned short* __restrict__ Kg,
    const unsigned short* __restrict__ Vg, unsigned short* __restrict__ O) {
  __shared__ unsigned short Kl[2][4096];
  __shared__ unsigned short Vl[2][4096];
  const int tid = threadIdx.x;
  const int wave = tid >> 6, lane = tid & 63;
  const int lrow = lane & 15, kg = lane >> 4;
  int bid = blockIdx.x;
  bid = (bid & 7) * 64 + (bid >> 3);  // XCD swizzle: 512 % 8 == 0, bijective
  const int bh = bid >> 4, qt = bid & 15;
  const int b = bh >> 4, h = bh & 15, kh = h >> 2;
  const char* Kt = (const char*)Kg + (size_t)((b * 4 + kh) * 64) * 8192;
  const char* Vt = (const char*)Vg + (size_t)((b * 4 + kh) * 64) * 8192;
  const unsigned short* Qb =
      Q + ((size_t)(b * 16 + h) * 2048 + qt * 128 + wave * 32) * 128;
  bf16x8 qfA[4], qfB[4];
#pragma unroll
  for (int c = 0; c < 4; ++c) {
    qfA[c] = *(const bf16x8*)(Qb + lrow * 128 + c * 32 + kg * 8);
    qfB[c] = *(const bf16x8*)(Qb + (16 + lrow) * 128 + c * 32 + kg * 8);
  }
  const f32x4 zero = {0.f, 0.f, 0.f, 0.f};
  f32x4 accA[8], accB[8];
#pragma unroll
  for (int c = 0; c < 8; ++c) { accA[c] = zero; accB[c] = zero; }
  float mA = -1e30f, lA = 0.f, mB = -1e30f, lB = 0.f;
  const int xr = (lrow & 7) << 4;

  const int o1 = wave * 1024 + lane * 16;
  const int o2 = 4096 + wave * 1024 + lane * 16;
  const int d1 = wave * 1024;
  const int d2 = 4096 + wave * 1024;

  // softmax for one fragment (8 scores/lane), exp2 domain; returns P fragment
  auto softmax = [&](f32x4& s0, f32x4& s1, float& m, float& l, f32x4* acc) -> bf16x8 {
    float mx = fmaxf(fmaxf(fmaxf(s0[0], s0[1]), fmaxf(s0[2], s0[3])),
                     fmaxf(fmaxf(s1[0], s1[1]), fmaxf(s1[2], s1[3])));
    mx = fmaxf(mx, __shfl_xor(mx, 16));
    mx = fmaxf(mx, __shfl_xor(mx, 32));
    if (__any(mx > m + 8.f)) {  // defer-max (T13)
      float mn = fmaxf(m, mx);
      float sc = exp2f(m - mn);
      m = mn;
      l *= sc;
#pragma unroll
      for (int j = 0; j < 4; ++j) {
        float scq = __shfl(sc, (lane & 48) | (kg * 4 + j));
#pragma unroll
        for (int c = 0; c < 8; ++c) acc[c][j] *= scq;
      }
    }
    float p0[4], p1[4], sum = 0.f;
#pragma unroll
    for (int j = 0; j < 4; ++j) {
      p0[j] = exp2f(s0[j] - m);
      p1[j] = exp2f(s1[j] - m);
      sum += p0[j] + p1[j];
    }
    sum += __shfl_xor(sum, 16);
    sum += __shfl_xor(sum, 32);
    l += sum;
    union { bf16x8 v; unsigned u[4]; } pa;
    pa.u[0] = cvt_pk_bf16(p0[0], p0[1]);
    pa.u[1] = cvt_pk_bf16(p0[2], p0[3]);
    pa.u[2] = cvt_pk_bf16(p1[0], p1[1]);
    pa.u[3] = cvt_pk_bf16(p1[2], p1[3]);
    return pa.v;
  };

  // prologue: stage tile 0 into buf 0
  gload_lds16(Kt + o1, (char*)Kl[0] + d1);
  gload_lds16(Kt + o2, (char*)Kl[0] + d2);
  gload_lds16(Vt + o1, (char*)Vl[0] + d1);
  gload_lds16(Vt + o2, (char*)Vl[0] + d2);
  __syncthreads();

  for (int t = 0; t < 64; ++t) {
    const int cur = t & 1;
    if (t < 63) {  // stage next tile; drained by loop-end barrier
      const char* kt = Kt + (size_t)(t + 1) * 8192;
      const char* vt = Vt + (size_t)(t + 1) * 8192;
      gload_lds16(kt + o1, (char*)Kl[cur ^ 1] + d1);
      gload_lds16(kt + o2, (char*)Kl[cur ^ 1] + d2);
      gload_lds16(vt + o1, (char*)Vl[cur ^ 1] + d1);
      gload_lds16(vt + o2, (char*)Vl[cur ^ 1] + d2);
    }
    const unsigned short* Kb = Kl[cur];
    const unsigned short* Vb = Vl[cur];
    // S^T = K * Q^T : K-frags shared by both q-frags
    f32x4 s0a = zero, s1a = zero, s0b = zero, s1b = zero;
    __builtin_amdgcn_s_setprio(1);
#pragma unroll
    for (int c = 0; c < 4; ++c) {
      bf16x8 k0 = *(const bf16x8*)((const char*)Kb + lrow * 256 + ((c * 64 + kg * 16) ^ xr));
      bf16x8 k1 = *(const bf16x8*)((const char*)Kb + (16 + lrow) * 256 + ((c * 64 + kg * 16) ^ xr));
      s0a = __builtin_amdgcn_mfma_f32_16x16x32_bf16(k0, qfA[c], s0a, 0, 0, 0);
      s1a = __builtin_amdgcn_mfma_f32_16x16x32_bf16(k1, qfA[c], s1a, 0, 0, 0);
      s0b = __builtin_amdgcn_mfma_f32_16x16x32_bf16(k0, qfB[c], s0b, 0, 0, 0);
      s1b = __builtin_amdgcn_mfma_f32_16x16x32_bf16(k1, qfB[c], s1b, 0, 0, 0);
    }
    __builtin_amdgcn_s_setprio(0);
    // two independent softmax chains (ILP)
    bf16x8 paA = softmax(s0a, s1a, mA, lA, accA);
    bf16x8 paB = softmax(s0b, s1b, mB, lB, accB);
    // O += P * V : V-frag is one b128, shared by both frags
    __builtin_amdgcn_s_setprio(1);
#pragma unroll
    for (int c = 0; c < 8; ++c) {
      bf16x8 vf = *(const bf16x8*)((const char*)Vb + (c * 16 + lrow) * 64 + kg * 16);
      accA[c] = __builtin_amdgcn_mfma_f32_16x16x32_bf16(paA, vf, accA[c], 0, 0, 0);
      accB[c] = __builtin_amdgcn_mfma_f32_16x16x32_bf16(paB, vf, accB[c], 0, 0, 0);
    }
    __builtin_amdgcn_s_setprio(0);
    __syncthreads();  // drains vmcnt(0): next tile staged; buffers safe to swap
  }
  // epilogue
  float invA = 1.0f / lA, invB = 1.0f / lB;
#pragma unroll
  for (int j = 0; j < 4; ++j) {
    float iA = __shfl(invA, (lane & 48) | (kg * 4 + j));
    float iB = __shfl(invB, (lane & 48) | (kg * 4 + j));
    int srowA = qt * 128 + wave * 32 + kg * 4 + j;
    unsigned short* dA = O + (((size_t)b * 2048 + srowA) * 16 + h) * 128;
    unsigned short* dB = O + (((size_t)b * 2048 + srowA + 16) * 16 + h) * 128;
#pragma unroll
    for (int c = 0; c < 8; ++c) {
      dA[c * 16 + lrow] = f2bf(accA[c][j] * iA);
      dB[c * 16 + lrow] = f2bf(accB[c][j] * iB);
    }
  }
}

extern "C" void kernel_launch(void* const* d_in, const int* in_sizes, int n_in,
                              void* d_out, int out_size, void* d_ws, size_t ws_size,
                              hipStream_t stream) {
  const float* hs   = (const float*)d_in[0];
  const float* cosT = (const float*)d_in[1];
  const float* sinT = (const float*)d_in[2];
  const float* Wq   = (const float*)d_in[3];
  const float* Wk   = (const float*)d_in[4];
  const float* Wv   = (const float*)d_in[5];
  const float* Wo   = (const float*)d_in[6];
  const float* nqw  = (const float*)d_in[7];
  const float* nkw  = (const float*)d_in[8];
  float* out = (float*)d_out;

  char* ws = (char*)d_ws;
  unsigned short* X    = (unsigned short*)ws;               // 4096x2048 bf16
  unsigned short* Wqkv = X + 8388608;                       // 3072x2048 bf16
  unsigned short* WoB  = Wqkv + 6291456;                    // 2048x2048 bf16
  float* QKV           = (float*)(WoB + 4194304);           // 4096x3072 f32
  unsigned short* Qb   = (unsigned short*)(QKV + 12582912); // (B,H,S,D)
  unsigned short* Kg   = Qb + 8388608;                      // K tiles 4.19MB
  unsigned short* Vg   = Kg + 2097152;                      // V tiles 4.19MB
  unsigned short* Ob   = (unsigned short*)QKV;              // reuse QKV region

  cvt4<<<8192, 256, 0, stream>>>((const float4*)hs, (ushort4*)X, 2097152);
  cvt4<<<4096, 256, 0, stream>>>((const float4*)Wq, (ushort4*)Wqkv, 1048576);
  cvt4<<<1024, 256, 0, stream>>>((const float4*)Wk, (ushort4*)(Wqkv + 4194304), 262144);
  cvt4<<<1024, 256, 0, stream>>>((const float4*)Wv, (ushort4*)(Wqkv + 5242880), 262144);
  cvt4<<<4096, 256, 0, stream>>>((const float4*)Wo, (ushort4*)WoB, 1048576);

  gemm_bt_f32<<<32 * 24, 256, 0, stream>>>(X, Wqkv, QKV, 4096, 3072, 2048);

  rms_rope<<<24576, 256, 0, stream>>>(QKV, cosT, sinT, nqw, nkw, Qb, Kg, Vg);

  attn64<<<512, 256, 0, stream>>>(Qb, Kg, Vg, Ob);

  gemm_bt_f32<<<32 * 16, 256, 0, stream>>>(Ob, WoB, out, 4096, 2048, 2048);
}

// Round 4
// 260.517 us; speedup vs baseline: 2.5762x; 1.0684x over previous
//
#include <hip/hip_runtime.h>

// Shapes (fixed): B=2, S=2048, HS=2048, H=16, KV=4, D=128, g=4

typedef __attribute__((ext_vector_type(8))) short bf16x8;
typedef __attribute__((ext_vector_type(4))) float f32x4;
typedef __attribute__((ext_vector_type(16))) float f32x16;

__device__ __forceinline__ unsigned short f2bf(float x) {
  union { float f; unsigned u; } v; v.f = x;
  unsigned r = v.u + 0x7fffu + ((v.u >> 16) & 1u);  // RN-even
  return (unsigned short)(r >> 16);
}

__device__ __forceinline__ unsigned cvt_pk_bf16(float lo, float hi) {
  unsigned r;
  asm("v_cvt_pk_bf16_f32 %0, %1, %2" : "=v"(r) : "v"(lo), "v"(hi));
  return r;
}

__device__ __forceinline__ void gload_lds16(const void* g, void* l) {
  __builtin_amdgcn_global_load_lds(
      (const __attribute__((address_space(1))) void*)g,
      (__attribute__((address_space(3))) void*)l, 16, 0, 0);
}

// ---------------- fp32 -> bf16 convert, 4 elems/thread ----------------
__global__ __launch_bounds__(256) void cvt4(const float4* __restrict__ in,
                                            ushort4* __restrict__ out, int n4) {
  int i = blockIdx.x * 256 + threadIdx.x;
  if (i < n4) {
    float4 v = in[i];
    out[i] = make_ushort4(f2bf(v.x), f2bf(v.y), f2bf(v.z), f2bf(v.w));
  }
}

// ---------------- bf16 GEMM, C[M][N] = sum_k A[m][k]*B[n][k], f32 out ----------------
__global__ __launch_bounds__(256) void gemm_bt_f32(
    const unsigned short* __restrict__ A, const unsigned short* __restrict__ B,
    float* __restrict__ C, int M, int N, int K) {
  __shared__ unsigned short lsA[128 * 32];
  __shared__ unsigned short lsB[128 * 32];
  const int tid = threadIdx.x;
  const int wave = tid >> 6;
  const int lane = tid & 63;
  const int lrow = lane & 15;
  const int kg = lane >> 4;
  const int nbn = N >> 7;
  const int bm = blockIdx.x / nbn;
  const int bn = blockIdx.x % nbn;
  const int m0 = bm << 7, n0 = bn << 7;
  const int wm = (wave >> 1) << 6, wn = (wave & 1) << 6;
  const f32x4 zero = {0.f, 0.f, 0.f, 0.f};
  f32x4 acc[4][4];
#pragma unroll
  for (int i = 0; i < 4; ++i)
#pragma unroll
    for (int j = 0; j < 4; ++j) acc[i][j] = zero;
  const int srow = tid >> 2;
  const int scol = (tid & 3) << 3;

  for (int k0 = 0; k0 < K; k0 += 32) {
    __syncthreads();
    gload_lds16(A + (size_t)(m0 + srow) * K + k0 + scol, (char*)lsA + wave * 1024);
    gload_lds16(A + (size_t)(m0 + 64 + srow) * K + k0 + scol, (char*)lsA + 4096 + wave * 1024);
    gload_lds16(B + (size_t)(n0 + srow) * K + k0 + scol, (char*)lsB + wave * 1024);
    gload_lds16(B + (size_t)(n0 + 64 + srow) * K + k0 + scol, (char*)lsB + 4096 + wave * 1024);
    __syncthreads();
    bf16x8 fa[4], fb[4];
#pragma unroll
    for (int i = 0; i < 4; ++i) {
      fa[i] = *(const bf16x8*)(lsA + ((wm + i * 16 + lrow) << 5) + (kg << 3));
      fb[i] = *(const bf16x8*)(lsB + ((wn + i * 16 + lrow) << 5) + (kg << 3));
    }
#pragma unroll
    for (int i = 0; i < 4; ++i)
#pragma unroll
      for (int j = 0; j < 4; ++j)
        acc[i][j] = __builtin_amdgcn_mfma_f32_16x16x32_bf16(fa[i], fb[j], acc[i][j], 0, 0, 0);
  }
#pragma unroll
  for (int i = 0; i < 4; ++i) {
#pragma unroll
    for (int j = 0; j < 4; ++j) {
      int col = n0 + wn + j * 16 + lrow;
      int rbase = m0 + wm + i * 16 + kg * 4;
#pragma unroll
      for (int t = 0; t < 4; ++t)
        C[(size_t)(rbase + t) * N + col] = acc[i][j][t];
    }
  }
}

// ---------------- RMSNorm + RoPE + scale; Q linear, K/V as pre-baked 16KB tiles ----
// Tiles cover 64 keys of one (b,kv): tb = ((b*4+kv)*32 + (s>>6)) * 16384 bytes.
// K tile: byte = key*256 + (d*2 ^ ((key&7)<<4))                          [key=s&63]
// V tile (for 32x32x16 B-frags): p=key>>4, vhi=(key>>2)&1, e=(key&3)|(((key>>3)&1)<<2)
//   byte = p*4096 + (d>>5)*1024 + vhi*512 + (d&31)*16 + e*2
// Q pre-scaled by D^-1/2 * log2(e)  (softmax in exp2 domain)
__global__ __launch_bounds__(256) void rms_rope(
    const float* __restrict__ QKV, const float* __restrict__ cosT,
    const float* __restrict__ sinT, const float* __restrict__ wq,
    const float* __restrict__ wk, unsigned short* __restrict__ Q,
    unsigned short* __restrict__ Kg, unsigned short* __restrict__ Vg) {
  int task = blockIdx.x * 4 + (threadIdx.x >> 6);
  int lane = threadIdx.x & 63;
  int row = task / 24;
  int slot = task - row * 24;
  int b = row >> 11, s = row & 2047;
  const float* x = QKV + (size_t)row * 3072 + slot * 128;
  float x1 = x[lane], x2 = x[lane + 64];
  if (slot < 20) {
    float ss = x1 * x1 + x2 * x2;
#pragma unroll
    for (int msk = 1; msk < 64; msk <<= 1) ss += __shfl_xor(ss, msk);
    float inv = rsqrtf(ss * (1.0f / 128.0f) + 1e-6f);
    const float* w = (slot < 16) ? wq : wk;
    x1 *= inv * w[lane];
    x2 *= inv * w[lane + 64];
    float c1 = cosT[s * 128 + lane], c2 = cosT[s * 128 + lane + 64];
    float sn1 = sinT[s * 128 + lane], sn2 = sinT[s * 128 + lane + 64];
    float o1 = x1 * c1 - x2 * sn1;
    float o2 = x2 * c2 + x1 * sn2;
    if (slot < 16) {
      const float qs = 0.08838834764831845f * 1.4426950408889634f;  // D^-1/2 * log2(e)
      o1 *= qs; o2 *= qs;
    }
    x1 = o1; x2 = o2;
  }
  if (slot < 16) {
    unsigned short* dst = Q + (((size_t)b * 16 + slot) * 2048 + s) * 128;
    dst[lane] = f2bf(x1);
    dst[lane + 64] = f2bf(x2);
  } else {
    int kv = (slot - 16) & 3;
    size_t tb = ((size_t)((b * 4 + kv) * 32) + (s >> 6)) * 16384;
    int key = s & 63;
    if (slot < 20) {
      char* base = (char*)Kg + tb;
      int xr = (key & 7) << 4;
      *(unsigned short*)(base + key * 256 + ((lane * 2) ^ xr)) = f2bf(x1);
      *(unsigned short*)(base + key * 256 + (((lane + 64) * 2) ^ xr)) = f2bf(x2);
    } else {
      char* base = (char*)Vg + tb;
      int p = key >> 4;
      int vhi = (key >> 2) & 1;
      int e = (key & 3) | (((key >> 3) & 1) << 2);
      int off = p * 4096 + vhi * 512 + e * 2;
      int d1 = lane, d2 = lane + 64;
      *(unsigned short*)(base + off + (d1 >> 5) * 1024 + (d1 & 31) * 16) = f2bf(x1);
      *(unsigned short*)(base + off + (d2 >> 5) * 1024 + (d2 & 31) * 16) = f2bf(x2);
    }
  }
}

// ---------------- flash attention: 32x32x16 MFMA, KVBLK=64, lane-local softmax ----
// Wave owns 32 q-rows. S^T = K*Q^T: lane holds 32 scores of q=lane&31 across
// s0/s1 regs (key = kb*32 + (r&3)+8*(r>>2)+4*hi). PV: O[q][d], q=(r&3)+8*(r>>2)+4*hi,
// d = c*32 + (lane&31).
__global__ __launch_bounds__(256, 2) void attn64(
    const unsigned short* __restrict__ Q, const unsigned short* __restrict__ Kg,
    const unsigned short* __restrict__ Vg, unsigned short* __restrict__ O) {
  __shared__ unsigned short Kl[2][8192];   // 16KB per tile (64 keys x 128d)
  __shared__ unsigned short Vl[2][8192];
  const int tid = threadIdx.x;
  const int wave = tid >> 6, lane = tid & 63;
  const int l31 = lane & 31, hi = lane >> 5;
  int bid = blockIdx.x;
  bid = (bid & 7) * 64 + (bid >> 3);  // XCD swizzle: 512 % 8 == 0, bijective
  const int bh = bid >> 4, qt = bid & 15;
  const int b = bh >> 4, h = bh & 15, kh = h >> 2;
  const char* Kt = (const char*)Kg + (size_t)(b * 4 + kh) * 524288;
  const char* Vt = (const char*)Vg + (size_t)(b * 4 + kh) * 524288;
  const unsigned short* Qb =
      Q + ((size_t)(b * 16 + h) * 2048 + qt * 128 + wave * 32) * 128;
  bf16x8 qf[8];
#pragma unroll
  for (int s = 0; s < 8; ++s)
    qf[s] = *(const bf16x8*)(Qb + l31 * 128 + s * 16 + hi * 8);
  f32x16 acc[4];
#pragma unroll
  for (int c = 0; c < 4; ++c)
#pragma unroll
    for (int r = 0; r < 16; ++r) acc[c][r] = 0.f;
  float m = -1e30f, lsum = 0.f;
  const int xrk = (l31 & 7) << 4;

  // prologue: stage tile 0 into buf 0 (K 16KB + V 16KB, 4 calls each)
#pragma unroll
  for (int c = 0; c < 4; ++c) {
    gload_lds16(Kt + c * 4096 + tid * 16, (char*)Kl[0] + c * 4096 + wave * 1024);
    gload_lds16(Vt + c * 4096 + tid * 16, (char*)Vl[0] + c * 4096 + wave * 1024);
  }
  __syncthreads();

  for (int t = 0; t < 32; ++t) {
    const int cur = t & 1;
    if (t < 31) {  // prefetch next tile; drained by loop-end barrier
      const char* kt = Kt + (size_t)(t + 1) * 16384;
      const char* vt = Vt + (size_t)(t + 1) * 16384;
#pragma unroll
      for (int c = 0; c < 4; ++c) {
        gload_lds16(kt + c * 4096 + tid * 16, (char*)Kl[cur ^ 1] + c * 4096 + wave * 1024);
        gload_lds16(vt + c * 4096 + tid * 16, (char*)Vl[cur ^ 1] + c * 4096 + wave * 1024);
      }
    }
    const char* Kb = (const char*)Kl[cur];
    const char* Vb = (const char*)Vl[cur];
    // S^T = K * Q^T: s0 keys 0-31, s1 keys 32-63
    f32x16 s0, s1;
#pragma unroll
    for (int r = 0; r < 16; ++r) { s0[r] = 0.f; s1[r] = 0.f; }
    __builtin_amdgcn_s_setprio(1);
#pragma unroll
    for (int s = 0; s < 8; ++s) {
      int xo = (s * 32 + hi * 16) ^ xrk;
      bf16x8 k0 = *(const bf16x8*)(Kb + l31 * 256 + xo);
      bf16x8 k1 = *(const bf16x8*)(Kb + (32 + l31) * 256 + xo);
      s0 = __builtin_amdgcn_mfma_f32_32x32x16_bf16(k0, qf[s], s0, 0, 0, 0);
      s1 = __builtin_amdgcn_mfma_f32_32x32x16_bf16(k1, qf[s], s1, 0, 0, 0);
    }
    __builtin_amdgcn_s_setprio(0);
    // lane-local softmax over 32 scores (q = l31), one cross-half shfl each
    float t8[8];
#pragma unroll
    for (int r = 0; r < 8; ++r)
      t8[r] = fmaxf(fmaxf(s0[r], s0[r + 8]), fmaxf(s1[r], s1[r + 8]));
#pragma unroll
    for (int r = 0; r < 4; ++r) t8[r] = fmaxf(t8[r], t8[r + 4]);
    float mx = fmaxf(fmaxf(t8[0], t8[1]), fmaxf(t8[2], t8[3]));
    mx = fmaxf(mx, __shfl_xor(mx, 32));
    if (__any(mx > m + 8.f)) {  // defer-max (T13)
      float mn = fmaxf(m, mx);
      float sc = exp2f(m - mn);
      m = mn;
      lsum *= sc;
#pragma unroll
      for (int r = 0; r < 16; ++r) {
        float scq = __shfl(sc, (r & 3) + 8 * (r >> 2) + 4 * hi);
#pragma unroll
        for (int c = 0; c < 4; ++c) acc[c][r] *= scq;
      }
    }
    float p0[16], p1[16];
#pragma unroll
    for (int r = 0; r < 16; ++r) {
      p0[r] = exp2f(s0[r] - m);
      p1[r] = exp2f(s1[r] - m);
    }
    float u8[8];
#pragma unroll
    for (int r = 0; r < 8; ++r) u8[r] = (p0[r] + p0[r + 8]) + (p1[r] + p1[r + 8]);
#pragma unroll
    for (int r = 0; r < 4; ++r) u8[r] += u8[r + 4];
    float sum = (u8[0] + u8[1]) + (u8[2] + u8[3]);
    sum += __shfl_xor(sum, 32);
    lsum += sum;
    // P -> 4 A-frags: pa[p] elem e = P[key = 16p + (e&3)+8*(e>>2)+4*hi]
    union { bf16x8 v[4]; unsigned w[16]; } pa;
#pragma unroll
    for (int r = 0; r < 4; ++r) {
      pa.w[r]      = cvt_pk_bf16(p0[2 * r], p0[2 * r + 1]);
      pa.w[4 + r]  = cvt_pk_bf16(p0[8 + 2 * r], p0[9 + 2 * r]);
      pa.w[8 + r]  = cvt_pk_bf16(p1[2 * r], p1[2 * r + 1]);
      pa.w[12 + r] = cvt_pk_bf16(p1[8 + 2 * r], p1[9 + 2 * r]);
    }
    // O += P * V : 4 key-pairs x 4 d-chunks, conflict-free lane-contiguous reads
    __builtin_amdgcn_s_setprio(1);
#pragma unroll
    for (int p = 0; p < 4; ++p)
#pragma unroll
      for (int c = 0; c < 4; ++c) {
        bf16x8 vf = *(const bf16x8*)(Vb + p * 4096 + c * 1024 + hi * 512 + l31 * 16);
        acc[c] = __builtin_amdgcn_mfma_f32_32x32x16_bf16(pa.v[p], vf, acc[c], 0, 0, 0);
      }
    __builtin_amdgcn_s_setprio(0);
    __syncthreads();  // drains vmcnt(0): next tile staged; buffers safe to swap
  }
  // epilogue: acc[c][r] = O[q][d=c*32+l31], q = (r&3)+8*(r>>2)+4*hi
  float inv = 1.0f / lsum;
#pragma unroll
  for (int r = 0; r < 16; ++r) {
    int q = (r & 3) + 8 * (r >> 2) + 4 * hi;
    float invq = __shfl(inv, q);
    int srow = qt * 128 + wave * 32 + q;
    unsigned short* dst = O + (((size_t)b * 2048 + srow) * 16 + h) * 128;
#pragma unroll
    for (int c = 0; c < 4; ++c)
      dst[c * 32 + l31] = f2bf(acc[c][r] * invq);
  }
}

extern "C" void kernel_launch(void* const* d_in, const int* in_sizes, int n_in,
                              void* d_out, int out_size, void* d_ws, size_t ws_size,
                              hipStream_t stream) {
  const float* hs   = (const float*)d_in[0];
  const float* cosT = (const float*)d_in[1];
  const float* sinT = (const float*)d_in[2];
  const float* Wq   = (const float*)d_in[3];
  const float* Wk   = (const float*)d_in[4];
  const float* Wv   = (const float*)d_in[5];
  const float* Wo   = (const float*)d_in[6];
  const float* nqw  = (const float*)d_in[7];
  const float* nkw  = (const float*)d_in[8];
  float* out = (float*)d_out;

  char* ws = (char*)d_ws;
  unsigned short* X    = (unsigned short*)ws;               // 4096x2048 bf16
  unsigned short* Wqkv = X + 8388608;                       // 3072x2048 bf16
  unsigned short* WoB  = Wqkv + 6291456;                    // 2048x2048 bf16
  float* QKV           = (float*)(WoB + 4194304);           // 4096x3072 f32
  unsigned short* Qb   = (unsigned short*)(QKV + 12582912); // (B,H,S,D)
  unsigned short* Kg   = Qb + 8388608;                      // K tiles 4.19MB
  unsigned short* Vg   = Kg + 2097152;                      // V tiles 4.19MB
  unsigned short* Ob   = (unsigned short*)QKV;              // reuse QKV region

  cvt4<<<8192, 256, 0, stream>>>((const float4*)hs, (ushort4*)X, 2097152);
  cvt4<<<4096, 256, 0, stream>>>((const float4*)Wq, (ushort4*)Wqkv, 1048576);
  cvt4<<<1024, 256, 0, stream>>>((const float4*)Wk, (ushort4*)(Wqkv + 4194304), 262144);
  cvt4<<<1024, 256, 0, stream>>>((const float4*)Wv, (ushort4*)(Wqkv + 5242880), 262144);
  cvt4<<<4096, 256, 0, stream>>>((const float4*)Wo, (ushort4*)WoB, 1048576);

  gemm_bt_f32<<<32 * 24, 256, 0, stream>>>(X, Wqkv, QKV, 4096, 3072, 2048);

  rms_rope<<<24576, 256, 0, stream>>>(QKV, cosT, sinT, nqw, nkw, Qb, Kg, Vg);

  attn64<<<512, 256, 0, stream>>>(Qb, Kg, Vg, Ob);

  gemm_bt_f32<<<32 * 16, 256, 0, stream>>>(Ob, WoB, out, 4096, 2048, 2048);
}